// Round 1
// baseline (406.068 us; speedup 1.0000x reference)
//
#include <hip/hip_runtime.h>
#include <stdint.h>

// Problem: S=2048, B=32, H=1024, NL=2
//   scores[b,s] = v . tanh( W1 @ hidden[-1,b] + W2 @ enc[s,b] + bias )
//   out = softmax_s(scores)  -> [B, S] f32
// Dominant cost: GEMM [M=65536,K=1024] x [N=1024,K=1024]^T (137 GFLOP), done in
// bf16 MFMA (error budget analysis: score err std ~8e-4 << 0.01 slack).

#define S_LEN 2048
#define B_SZ 32
#define H_SZ 1024
#define M_TOT (S_LEN * B_SZ)   // 65536
#define K_TOT H_SZ             // 1024
#define NCB 8                  // col-blocks = N / 128

typedef __attribute__((ext_vector_type(8))) short short8;
typedef __attribute__((ext_vector_type(4))) float f32x4;

static __device__ __forceinline__ unsigned short f2bf(float x) {
  // round-to-nearest-even f32 -> bf16
  uint32_t u = __builtin_bit_cast(uint32_t, x);
  u += 0x7FFFu + ((u >> 16) & 1u);
  return (unsigned short)(u >> 16);
}

static __device__ __forceinline__ float fast_tanh(float x) {
  float e = __expf(2.0f * x);
  return 1.0f - 2.0f / (e + 1.0f);
}

// ---------- prep 1: u[b][h] = dot(attn_w[h, 0:H], hidden[-1, b, :]) + attn_b[h]
__global__ void __launch_bounds__(256) prep_u_kernel(
    const float* __restrict__ hidden, const float* __restrict__ attn_w,
    const float* __restrict__ attn_b, float* __restrict__ u) {
  __shared__ float hs[H_SZ];
  const int b = blockIdx.y, hc = blockIdx.x, tid = threadIdx.x;
  const float* hid = hidden + (size_t)1 * B_SZ * H_SZ + (size_t)b * H_SZ;  // last layer
  for (int i = tid; i < H_SZ; i += 256) hs[i] = hid[i];
  __syncthreads();
  const int h = hc * 256 + tid;
  const float* wrow = attn_w + (size_t)h * (2 * H_SZ);
  float s = 0.f;
#pragma unroll 4
  for (int k = 0; k < H_SZ; k += 4) {
    float4 w4 = *reinterpret_cast<const float4*>(wrow + k);
    s += w4.x * hs[k] + w4.y * hs[k + 1] + w4.z * hs[k + 2] + w4.w * hs[k + 3];
  }
  u[(size_t)b * H_SZ + h] = s + attn_b[h];
}

// ---------- prep 2: W2 (= attn_w[:, H:2H]) -> bf16 row-major [N=1024][K=1024]
__global__ void __launch_bounds__(256) prep_w2_kernel(
    const float* __restrict__ attn_w, unsigned short* __restrict__ Bt) {
  const int idx = blockIdx.x * 256 + threadIdx.x;  // 4 elems each
  const int base = idx * 4;
  const int n = base >> 10, k = base & 1023;
  float4 w = *reinterpret_cast<const float4*>(attn_w + (size_t)n * 2048 + 1024 + k);
  ushort4 o;
  o.x = f2bf(w.x); o.y = f2bf(w.y); o.z = f2bf(w.z); o.w = f2bf(w.w);
  *reinterpret_cast<ushort4*>(Bt + base) = o;
}

// ---------- main fused GEMM:
//   per 128x128 tile of y = enc @ W2^T:  acc -> tanh(acc + u) . v -> row partial sums
// grid: (8 col-blocks, 512 row-blocks); 256 threads = 4 waves (2x2 of 64x64).
__global__ void __launch_bounds__(256) gemm_fused_kernel(
    const float* __restrict__ A,            // enc as [M][K] f32
    const unsigned short* __restrict__ Bt,  // W2 bf16 [1024][1024]
    const float* __restrict__ u,            // [32][1024] f32
    const float* __restrict__ v,            // [1024] f32
    float* __restrict__ pscore) {           // [8][M] f32 partials
  __shared__ unsigned short As[128 * 32];
  __shared__ unsigned short Bs[128 * 32];
  __shared__ float rowsum[2][128];

  const int tid = threadIdx.x;
  const int wid = tid >> 6, lane = tid & 63;
  const int wr = wid >> 1, wc = wid & 1;
  const int cb = blockIdx.x;
  const int brow = blockIdx.y * 128;
  const int bcol = cb * 128;

  // A staging: thread t handles row t/2, 16 floats at col (t&1)*16
  const int arow_st = tid >> 1;
  const int acol_st = (tid & 1) * 16;
  const float* Ag = A + (size_t)(brow + arow_st) * K_TOT + acol_st;
  unsigned short* AsW = As + arow_st * 32 + acol_st;

  // B staging via global_load_lds: wave wid covers chunks {2*wid, 2*wid+1},
  // each chunk = 16 rows (1 KiB LDS), lane l -> row chunk*16 + l/4, col (l&3)*8
  const int chunk0 = wid * 2;
  const unsigned short* Bg0 =
      Bt + (size_t)(bcol + chunk0 * 16 + (lane >> 2)) * K_TOT + (lane & 3) * 8;

  f32x4 acc[4][4];
#pragma unroll
  for (int i = 0; i < 4; ++i)
#pragma unroll
    for (int j = 0; j < 4; ++j) acc[i][j] = (f32x4){0.f, 0.f, 0.f, 0.f};

  const int fr = lane & 15;         // fragment row index
  const int kseg = (lane >> 4) * 8; // k-slice start per lane group

  for (int k0 = 0; k0 < K_TOT; k0 += 32) {
    __syncthreads();  // previous tile's LDS reads complete
    // A: f32 -> bf16 reg-staging
    const float4* ap = reinterpret_cast<const float4*>(Ag + k0);
    float4 f0 = ap[0], f1 = ap[1], f2 = ap[2], f3 = ap[3];
    uint4 w0, w1;
    w0.x = (uint32_t)f2bf(f0.x) | ((uint32_t)f2bf(f0.y) << 16);
    w0.y = (uint32_t)f2bf(f0.z) | ((uint32_t)f2bf(f0.w) << 16);
    w0.z = (uint32_t)f2bf(f1.x) | ((uint32_t)f2bf(f1.y) << 16);
    w0.w = (uint32_t)f2bf(f1.z) | ((uint32_t)f2bf(f1.w) << 16);
    w1.x = (uint32_t)f2bf(f2.x) | ((uint32_t)f2bf(f2.y) << 16);
    w1.y = (uint32_t)f2bf(f2.z) | ((uint32_t)f2bf(f2.w) << 16);
    w1.z = (uint32_t)f2bf(f3.x) | ((uint32_t)f2bf(f3.y) << 16);
    w1.w = (uint32_t)f2bf(f3.z) | ((uint32_t)f2bf(f3.w) << 16);
    *reinterpret_cast<uint4*>(AsW) = w0;
    *reinterpret_cast<uint4*>(AsW + 8) = w1;
    // B: direct global -> LDS (16B/lane, wave-uniform LDS base + lane*16)
    __builtin_amdgcn_global_load_lds(
        (const __attribute__((address_space(1))) void*)(Bg0 + k0),
        (__attribute__((address_space(3))) void*)(Bs + chunk0 * 512), 16, 0, 0);
    __builtin_amdgcn_global_load_lds(
        (const __attribute__((address_space(1))) void*)(Bg0 + 16 * K_TOT + k0),
        (__attribute__((address_space(3))) void*)(Bs + chunk0 * 512 + 512), 16, 0, 0);
    __syncthreads();  // staging complete (compiler drains vmcnt/lgkmcnt)

    short8 af[4], bf[4];
#pragma unroll
    for (int i = 0; i < 4; ++i)
      af[i] = *reinterpret_cast<const short8*>(As + (wr * 64 + i * 16 + fr) * 32 + kseg);
#pragma unroll
    for (int j = 0; j < 4; ++j)
      bf[j] = *reinterpret_cast<const short8*>(Bs + (wc * 64 + j * 16 + fr) * 32 + kseg);
#pragma unroll
    for (int i = 0; i < 4; ++i)
#pragma unroll
      for (int j = 0; j < 4; ++j)
        acc[i][j] = __builtin_amdgcn_mfma_f32_16x16x32_bf16(af[i], bf[j], acc[i][j], 0, 0, 0);
  }

  // Epilogue: scores partial = sum_h v[h] * tanh(y + u[b,h]) over this tile's 128 h's
  float vv[4];
#pragma unroll
  for (int j = 0; j < 4; ++j) vv[j] = v[bcol + wc * 64 + j * 16 + fr];

  const int g4 = (lane >> 4) * 4;
#pragma unroll
  for (int i = 0; i < 4; ++i) {
#pragma unroll
    for (int reg = 0; reg < 4; ++reg) {
      const int rloc = wr * 64 + i * 16 + g4 + reg;  // C/D row = (lane>>4)*4+reg
      const int bb = (brow + rloc) & (B_SZ - 1);     // m = s*B + b -> b = m % 32
      float rs = 0.f;
#pragma unroll
      for (int j = 0; j < 4; ++j) {
        const int h = bcol + wc * 64 + j * 16 + fr;  // C/D col = lane&15
        float val = acc[i][j][reg] + u[(size_t)bb * H_SZ + h];
        rs += vv[j] * fast_tanh(val);
      }
      // reduce across the 16 lanes sharing this row
      rs += __shfl_xor(rs, 1);
      rs += __shfl_xor(rs, 2);
      rs += __shfl_xor(rs, 4);
      rs += __shfl_xor(rs, 8);
      if (fr == 0) rowsum[wc][rloc] = rs;
    }
  }
  __syncthreads();
  if (tid < 128) {
    // deterministic combine of the two col-half waves; one writer per element
    pscore[(size_t)cb * M_TOT + brow + tid] = rowsum[0][tid] + rowsum[1][tid];
  }
}

// ---------- softmax over s per batch row b; also sums the 8 col-block partials
__global__ void __launch_bounds__(256) softmax_kernel(
    const float* __restrict__ ps, float* __restrict__ out) {
  const int b = blockIdx.x, tid = threadIdx.x;
  const int wid = tid >> 6, lane = tid & 63;
  __shared__ float sred[4];
  float vals[8];
  float mx = -1e30f;
#pragma unroll
  for (int ii = 0; ii < 8; ++ii) {
    const int s = ii * 256 + tid;
    float sum = 0.f;
#pragma unroll
    for (int cbk = 0; cbk < NCB; ++cbk) sum += ps[(size_t)cbk * M_TOT + s * B_SZ + b];
    vals[ii] = sum;
    mx = fmaxf(mx, sum);
  }
#pragma unroll
  for (int m = 1; m < 64; m <<= 1) mx = fmaxf(mx, __shfl_xor(mx, m));
  if (lane == 0) sred[wid] = mx;
  __syncthreads();
  mx = fmaxf(fmaxf(sred[0], sred[1]), fmaxf(sred[2], sred[3]));
  __syncthreads();
  float es = 0.f;
#pragma unroll
  for (int ii = 0; ii < 8; ++ii) {
    vals[ii] = __expf(vals[ii] - mx);
    es += vals[ii];
  }
#pragma unroll
  for (int m = 1; m < 64; m <<= 1) es += __shfl_xor(es, m);
  if (lane == 0) sred[wid] = es;
  __syncthreads();
  es = sred[0] + sred[1] + sred[2] + sred[3];
  const float inv = 1.0f / es;
#pragma unroll
  for (int ii = 0; ii < 8; ++ii) out[(size_t)b * S_LEN + ii * 256 + tid] = vals[ii] * inv;
}

extern "C" void kernel_launch(void* const* d_in, const int* in_sizes, int n_in,
                              void* d_out, int out_size, void* d_ws, size_t ws_size,
                              hipStream_t stream) {
  const float* hidden = (const float*)d_in[0];   // [2,32,1024]
  const float* enc    = (const float*)d_in[1];   // [2048,32,1024] == A [65536][1024]
  const float* attn_w = (const float*)d_in[2];   // [1024][2048]
  const float* attn_b = (const float*)d_in[3];   // [1024]
  const float* v      = (const float*)d_in[4];   // [1024]
  float* out = (float*)d_out;                    // [32][2048]

  // workspace layout: Bt bf16 2MB | u f32 128KB | pscore f32 2MB  (~4.2MB total)
  char* w = (char*)d_ws;
  unsigned short* Bt = (unsigned short*)w;                              // 1024*1024 bf16
  float* u  = (float*)(w + (size_t)2 * 1024 * 1024);                    // 32*1024 f32
  float* ps = (float*)(w + (size_t)2 * 1024 * 1024 + 128 * 1024);       // 8*65536 f32

  prep_u_kernel<<<dim3(4, 32), 256, 0, stream>>>(hidden, attn_w, attn_b, u);
  prep_w2_kernel<<<1024, 256, 0, stream>>>(attn_w, Bt);
  gemm_fused_kernel<<<dim3(NCB, M_TOT / 128), 256, 0, stream>>>(enc, Bt, u, v, ps);
  softmax_kernel<<<B_SZ, 256, 0, stream>>>(ps, out);
}

// Round 5
// 350.415 us; speedup vs baseline: 1.1588x; 1.1588x over previous
//
#include <hip/hip_runtime.h>
#include <stdint.h>

// scores[b,s] = v . tanh( W1@hidden[-1,b] + W2@enc[s,b] + bias ); out = softmax_s
// GEMM: [M=65536,K=1024] x [N=1024,K=1024]^T in bf16 MFMA.
// This version: bf16 prepass writes enc/W2 as pre-swizzled LDS-image tiles
// (conflict-free ds_read_b128), GEMM uses global_load_lds for both operands,
// XCD-swizzled block mapping colocates the 8 col-blocks of each A panel.

#define S_LEN 2048
#define B_SZ 32
#define H_SZ 1024
#define M_TOT (S_LEN * B_SZ)   // 65536
#define K_TOT H_SZ             // 1024
#define NCB 8                  // col-blocks = N / 128
#define BK 64
#define TILE_SHORTS 8192       // 128 rows * 64 k * bf16 = 16 KB

typedef __attribute__((ext_vector_type(8))) short short8;
typedef __attribute__((ext_vector_type(4))) float f32x4;

static __device__ __forceinline__ unsigned short f2bf(float x) {
  uint32_t u = __builtin_bit_cast(uint32_t, x);
  u += 0x7FFFu + ((u >> 16) & 1u);
  return (unsigned short)(u >> 16);
}
static __device__ __forceinline__ uint32_t pack2(float a, float b) {
  return (uint32_t)f2bf(a) | ((uint32_t)f2bf(b) << 16);
}
static __device__ __forceinline__ float fast_tanh(float x) {
  float e = __expf(2.0f * x);
  return 1.0f - 2.0f / (e + 1.0f);
}

// ---------- u[b][h] = dot(attn_w[h, 0:H], hidden[-1,b,:]) + attn_b[h]
__global__ void __launch_bounds__(256) prep_u_kernel(
    const float* __restrict__ hidden, const float* __restrict__ attn_w,
    const float* __restrict__ attn_b, float* __restrict__ u) {
  __shared__ float hs[H_SZ];
  const int b = blockIdx.y, hc = blockIdx.x, tid = threadIdx.x;
  const float* hid = hidden + (size_t)1 * B_SZ * H_SZ + (size_t)b * H_SZ;
  for (int i = tid; i < H_SZ; i += 256) hs[i] = hid[i];
  __syncthreads();
  const int h = hc * 256 + tid;
  const float* wrow = attn_w + (size_t)h * (2 * H_SZ);
  float s = 0.f;
#pragma unroll 4
  for (int k = 0; k < H_SZ; k += 4) {
    float4 w4 = *reinterpret_cast<const float4*>(wrow + k);
    s += w4.x * hs[k] + w4.y * hs[k + 1] + w4.z * hs[k + 2] + w4.w * hs[k + 3];
  }
  u[(size_t)b * H_SZ + h] = s + attn_b[h];
}

// ---------- enc f32 -> bf16 LDS-image tiles.
// Image layout: tile (rp, kb) at (rp*16+kb)*8192 shorts; within tile:
// row r (0..127) * 64 shorts, 16B slot s8 stored at (s8 ^ (r&7)).
__global__ void __launch_bounds__(256) prep_a_kernel(
    const float* __restrict__ enc, unsigned short* __restrict__ Aimg) {
  const int idx = blockIdx.x * 256 + threadIdx.x;   // [0, M_TOT*128)
  const int m = idx >> 7, sl = idx & 127;
  const int kb = sl >> 3, s8 = sl & 7;
  const float4* src =
      reinterpret_cast<const float4*>(enc + (size_t)m * K_TOT + kb * BK + s8 * 8);
  float4 f0 = src[0], f1 = src[1];
  uint4 o;
  o.x = pack2(f0.x, f0.y); o.y = pack2(f0.z, f0.w);
  o.z = pack2(f1.x, f1.y); o.w = pack2(f1.z, f1.w);
  const int row = m & 127;
  const size_t tile = (size_t)(m >> 7) * 16 + kb;
  unsigned short* dst = Aimg + tile * TILE_SHORTS + row * 64 + ((s8 ^ (row & 7)) << 3);
  *reinterpret_cast<uint4*>(dst) = o;
}

// ---------- W2 (= attn_w[:, H:2H]) -> bf16 LDS-image tiles, same layout
__global__ void __launch_bounds__(256) prep_b_kernel(
    const float* __restrict__ attn_w, unsigned short* __restrict__ Bimg) {
  const int idx = blockIdx.x * 256 + threadIdx.x;   // [0, 1024*128)
  const int n = idx >> 7, sl = idx & 127;
  const int kb = sl >> 3, s8 = sl & 7;
  const float4* src = reinterpret_cast<const float4*>(
      attn_w + (size_t)n * 2048 + 1024 + kb * BK + s8 * 8);
  float4 f0 = src[0], f1 = src[1];
  uint4 o;
  o.x = pack2(f0.x, f0.y); o.y = pack2(f0.z, f0.w);
  o.z = pack2(f1.x, f1.y); o.w = pack2(f1.z, f1.w);
  const int row = n & 127;
  const size_t tile = (size_t)(n >> 7) * 16 + kb;
  unsigned short* dst = Bimg + tile * TILE_SHORTS + row * 64 + ((s8 ^ (row & 7)) << 3);
  *reinterpret_cast<uint4*>(dst) = o;
}

// ---------- main GEMM (pure bf16, both operands via global_load_lds)
// grid: 4096 blocks 1-D, XCD-swizzled: xcd = wg&7 owns row panels [xcd*64, +64),
// the 8 col-blocks of one panel are consecutive within an XCD (A L2-hot).
__global__ void __launch_bounds__(256) gemm_img_kernel(
    const unsigned short* __restrict__ Aimg, const unsigned short* __restrict__ Bimg,
    const float* __restrict__ u, const float* __restrict__ v,
    float* __restrict__ pscore) {
  __shared__ unsigned short As[TILE_SHORTS];
  __shared__ unsigned short Bs[TILE_SHORTS];
  __shared__ float rowsum[2][128];

  const int tid = threadIdx.x;
  const int wid = tid >> 6, lane = tid & 63;
  const int wr = wid >> 1, wc = wid & 1;

  const int wg = blockIdx.x;
  const int xcd = wg & 7, li = wg >> 3;
  const int rp = xcd * 64 + (li >> 3);
  const int cb = li & 7;
  const int brow = rp * 128, bcol = cb * 128;

  const unsigned short* Ag = Aimg + (size_t)rp * 16 * TILE_SHORTS;
  const unsigned short* Bg = Bimg + (size_t)cb * 16 * TILE_SHORTS;

  f32x4 acc[4][4];
#pragma unroll
  for (int i = 0; i < 4; ++i)
#pragma unroll
    for (int j = 0; j < 4; ++j) acc[i][j] = (f32x4){0.f, 0.f, 0.f, 0.f};

  const int fr = lane & 15, g = lane >> 4;
  // swizzled 16B-slot offsets (shorts) for the two K=32 halves of a BK=64 row
  const int soff0 = ((g) ^ (fr & 7)) << 3;
  const int soff1 = ((4 + g) ^ (fr & 7)) << 3;
  const int arow_base = (wr * 64 + fr) * 64;
  const int brow_base = (wc * 64 + fr) * 64;
  // staging: wave wid covers quarter wid of each tile; 4 loads x 1KB each
  const int stg = wid * 2048;  // shorts

  for (int kb = 0; kb < 16; ++kb) {
    __syncthreads();  // previous iteration's LDS reads complete
    const unsigned short* at = Ag + kb * TILE_SHORTS + stg + lane * 8;
    const unsigned short* bt = Bg + kb * TILE_SHORTS + stg + lane * 8;
#pragma unroll
    for (int j = 0; j < 4; ++j) {
      __builtin_amdgcn_global_load_lds(
          (const __attribute__((address_space(1))) void*)(at + j * 512),
          (__attribute__((address_space(3))) void*)(As + stg + j * 512), 16, 0, 0);
      __builtin_amdgcn_global_load_lds(
          (const __attribute__((address_space(1))) void*)(bt + j * 512),
          (__attribute__((address_space(3))) void*)(Bs + stg + j * 512), 16, 0, 0);
    }
    __syncthreads();  // staging complete

    short8 af[4], bf[4];
#pragma unroll
    for (int i = 0; i < 4; ++i)
      af[i] = *reinterpret_cast<const short8*>(As + arow_base + i * 1024 + soff0);
#pragma unroll
    for (int j = 0; j < 4; ++j)
      bf[j] = *reinterpret_cast<const short8*>(Bs + brow_base + j * 1024 + soff0);
#pragma unroll
    for (int i = 0; i < 4; ++i)
#pragma unroll
      for (int j = 0; j < 4; ++j)
        acc[i][j] = __builtin_amdgcn_mfma_f32_16x16x32_bf16(af[i], bf[j], acc[i][j], 0, 0, 0);
#pragma unroll
    for (int i = 0; i < 4; ++i)
      af[i] = *reinterpret_cast<const short8*>(As + arow_base + i * 1024 + soff1);
#pragma unroll
    for (int j = 0; j < 4; ++j)
      bf[j] = *reinterpret_cast<const short8*>(Bs + brow_base + j * 1024 + soff1);
#pragma unroll
    for (int i = 0; i < 4; ++i)
#pragma unroll
      for (int j = 0; j < 4; ++j)
        acc[i][j] = __builtin_amdgcn_mfma_f32_16x16x32_bf16(af[i], bf[j], acc[i][j], 0, 0, 0);
  }

  // Epilogue: partial scores = sum_h v[h] * tanh(y + u[b,h]) over this tile's cols
  float vv[4];
#pragma unroll
  for (int j = 0; j < 4; ++j) vv[j] = v[bcol + wc * 64 + j * 16 + fr];

  const int g4 = g * 4;
#pragma unroll
  for (int i = 0; i < 4; ++i) {
#pragma unroll
    for (int reg = 0; reg < 4; ++reg) {
      const int rloc = wr * 64 + i * 16 + g4 + reg;  // C/D row = (lane>>4)*4+reg
      const int bb = (brow + rloc) & (B_SZ - 1);     // m = s*B + b -> b = m & 31
      float rs = 0.f;
#pragma unroll
      for (int j = 0; j < 4; ++j) {
        const int h = bcol + wc * 64 + j * 16 + fr;  // C/D col = lane&15
        float val = acc[i][j][reg] + u[(size_t)bb * H_SZ + h];
        rs += vv[j] * fast_tanh(val);
      }
      rs += __shfl_xor(rs, 1);
      rs += __shfl_xor(rs, 2);
      rs += __shfl_xor(rs, 4);
      rs += __shfl_xor(rs, 8);
      if (fr == 0) rowsum[wc][rloc] = rs;
    }
  }
  __syncthreads();
  if (tid < 128)
    pscore[(size_t)cb * M_TOT + brow + tid] = rowsum[0][tid] + rowsum[1][tid];
}

// ================= fallback path (round-1, validated) for small ws =================
__global__ void __launch_bounds__(256) prep_w2_flat_kernel(
    const float* __restrict__ attn_w, unsigned short* __restrict__ Bt) {
  const int idx = blockIdx.x * 256 + threadIdx.x;
  const int base = idx * 4;
  const int n = base >> 10, k = base & 1023;
  float4 w = *reinterpret_cast<const float4*>(attn_w + (size_t)n * 2048 + 1024 + k);
  ushort4 o;
  o.x = f2bf(w.x); o.y = f2bf(w.y); o.z = f2bf(w.z); o.w = f2bf(w.w);
  *reinterpret_cast<ushort4*>(Bt + base) = o;
}

__global__ void __launch_bounds__(256) gemm_fused_kernel(
    const float* __restrict__ A, const unsigned short* __restrict__ Bt,
    const float* __restrict__ u, const float* __restrict__ v,
    float* __restrict__ pscore) {
  __shared__ unsigned short As[128 * 32];
  __shared__ unsigned short Bs[128 * 32];
  __shared__ float rowsum[2][128];
  const int tid = threadIdx.x;
  const int wid = tid >> 6, lane = tid & 63;
  const int wr = wid >> 1, wc = wid & 1;
  const int cb = blockIdx.x;
  const int brow = blockIdx.y * 128;
  const int bcol = cb * 128;
  const int arow_st = tid >> 1;
  const int acol_st = (tid & 1) * 16;
  const float* Ag = A + (size_t)(brow + arow_st) * K_TOT + acol_st;
  unsigned short* AsW = As + arow_st * 32 + acol_st;
  const int chunk0 = wid * 2;
  const unsigned short* Bg0 =
      Bt + (size_t)(bcol + chunk0 * 16 + (lane >> 2)) * K_TOT + (lane & 3) * 8;
  f32x4 acc[4][4];
#pragma unroll
  for (int i = 0; i < 4; ++i)
#pragma unroll
    for (int j = 0; j < 4; ++j) acc[i][j] = (f32x4){0.f, 0.f, 0.f, 0.f};
  const int fr = lane & 15;
  const int kseg = (lane >> 4) * 8;
  for (int k0 = 0; k0 < K_TOT; k0 += 32) {
    __syncthreads();
    const float4* ap = reinterpret_cast<const float4*>(Ag + k0);
    float4 f0 = ap[0], f1 = ap[1], f2 = ap[2], f3 = ap[3];
    uint4 w0, w1;
    w0.x = pack2(f0.x, f0.y); w0.y = pack2(f0.z, f0.w);
    w0.z = pack2(f1.x, f1.y); w0.w = pack2(f1.z, f1.w);
    w1.x = pack2(f2.x, f2.y); w1.y = pack2(f2.z, f2.w);
    w1.z = pack2(f3.x, f3.y); w1.w = pack2(f3.z, f3.w);
    *reinterpret_cast<uint4*>(AsW) = w0;
    *reinterpret_cast<uint4*>(AsW + 8) = w1;
    __builtin_amdgcn_global_load_lds(
        (const __attribute__((address_space(1))) void*)(Bg0 + k0),
        (__attribute__((address_space(3))) void*)(Bs + chunk0 * 512), 16, 0, 0);
    __builtin_amdgcn_global_load_lds(
        (const __attribute__((address_space(1))) void*)(Bg0 + 16 * K_TOT + k0),
        (__attribute__((address_space(3))) void*)(Bs + chunk0 * 512 + 512), 16, 0, 0);
    __syncthreads();
    short8 af[4], bf[4];
#pragma unroll
    for (int i = 0; i < 4; ++i)
      af[i] = *reinterpret_cast<const short8*>(As + (wr * 64 + i * 16 + fr) * 32 + kseg);
#pragma unroll
    for (int j = 0; j < 4; ++j)
      bf[j] = *reinterpret_cast<const short8*>(Bs + (wc * 64 + j * 16 + fr) * 32 + kseg);
#pragma unroll
    for (int i = 0; i < 4; ++i)
#pragma unroll
      for (int j = 0; j < 4; ++j)
        acc[i][j] = __builtin_amdgcn_mfma_f32_16x16x32_bf16(af[i], bf[j], acc[i][j], 0, 0, 0);
  }
  float vv[4];
#pragma unroll
  for (int j = 0; j < 4; ++j) vv[j] = v[bcol + wc * 64 + j * 16 + fr];
  const int g4 = (lane >> 4) * 4;
#pragma unroll
  for (int i = 0; i < 4; ++i) {
#pragma unroll
    for (int reg = 0; reg < 4; ++reg) {
      const int rloc = wr * 64 + i * 16 + g4 + reg;
      const int bb = (brow + rloc) & (B_SZ - 1);
      float rs = 0.f;
#pragma unroll
      for (int j = 0; j < 4; ++j) {
        const int h = bcol + wc * 64 + j * 16 + fr;
        float val = acc[i][j][reg] + u[(size_t)bb * H_SZ + h];
        rs += vv[j] * fast_tanh(val);
      }
      rs += __shfl_xor(rs, 1);
      rs += __shfl_xor(rs, 2);
      rs += __shfl_xor(rs, 4);
      rs += __shfl_xor(rs, 8);
      if (fr == 0) rowsum[wc][rloc] = rs;
    }
  }
  __syncthreads();
  if (tid < 128)
    pscore[(size_t)cb * M_TOT + brow + tid] = rowsum[0][tid] + rowsum[1][tid];
}
// ================= end fallback =================

__global__ void __launch_bounds__(256) softmax_kernel(
    const float* __restrict__ ps, float* __restrict__ out) {
  const int b = blockIdx.x, tid = threadIdx.x;
  const int wid = tid >> 6, lane = tid & 63;
  __shared__ float sred[4];
  float vals[8];
  float mx = -1e30f;
#pragma unroll
  for (int ii = 0; ii < 8; ++ii) {
    const int s = ii * 256 + tid;
    float sum = 0.f;
#pragma unroll
    for (int cbk = 0; cbk < NCB; ++cbk) sum += ps[(size_t)cbk * M_TOT + s * B_SZ + b];
    vals[ii] = sum;
    mx = fmaxf(mx, sum);
  }
#pragma unroll
  for (int m = 1; m < 64; m <<= 1) mx = fmaxf(mx, __shfl_xor(mx, m));
  if (lane == 0) sred[wid] = mx;
  __syncthreads();
  mx = fmaxf(fmaxf(sred[0], sred[1]), fmaxf(sred[2], sred[3]));
  __syncthreads();
  float es = 0.f;
#pragma unroll
  for (int ii = 0; ii < 8; ++ii) {
    vals[ii] = __expf(vals[ii] - mx);
    es += vals[ii];
  }
#pragma unroll
  for (int m = 1; m < 64; m <<= 1) es += __shfl_xor(es, m);
  if (lane == 0) sred[wid] = es;
  __syncthreads();
  es = sred[0] + sred[1] + sred[2] + sred[3];
  const float inv = 1.0f / es;
#pragma unroll
  for (int ii = 0; ii < 8; ++ii) out[(size_t)b * S_LEN + ii * 256 + tid] = vals[ii] * inv;
}

extern "C" void kernel_launch(void* const* d_in, const int* in_sizes, int n_in,
                              void* d_out, int out_size, void* d_ws, size_t ws_size,
                              hipStream_t stream) {
  const float* hidden = (const float*)d_in[0];   // [2,32,1024]
  const float* enc    = (const float*)d_in[1];   // [2048,32,1024] == A [65536][1024]
  const float* attn_w = (const float*)d_in[2];   // [1024][2048]
  const float* attn_b = (const float*)d_in[3];   // [1024]
  const float* v      = (const float*)d_in[4];   // [1024]
  float* out = (float*)d_out;                    // [32][2048]

  const size_t A_BYTES = (size_t)M_TOT * K_TOT * 2;      // 128 MB
  const size_t B_BYTES = (size_t)K_TOT * K_TOT * 2;      // 2 MB
  const size_t U_BYTES = (size_t)B_SZ * H_SZ * 4;        // 128 KB
  const size_t P_BYTES = (size_t)NCB * M_TOT * 4;        // 2 MB
  char* w = (char*)d_ws;

  if (ws_size >= A_BYTES + B_BYTES + U_BYTES + P_BYTES) {
    unsigned short* Aimg = (unsigned short*)w;
    unsigned short* Bimg = (unsigned short*)(w + A_BYTES);
    float* u  = (float*)(w + A_BYTES + B_BYTES);
    float* ps = (float*)(w + A_BYTES + B_BYTES + U_BYTES);
    prep_u_kernel<<<dim3(4, 32), 256, 0, stream>>>(hidden, attn_w, attn_b, u);
    prep_b_kernel<<<512, 256, 0, stream>>>(attn_w, Bimg);
    prep_a_kernel<<<M_TOT * 128 / 256, 256, 0, stream>>>(enc, Aimg);
    gemm_img_kernel<<<NCB * (M_TOT / 128), 256, 0, stream>>>(Aimg, Bimg, u, v, ps);
    softmax_kernel<<<B_SZ, 256, 0, stream>>>(ps, out);
  } else {
    // fallback: round-1 validated path (~4.2 MB ws)
    unsigned short* Bt = (unsigned short*)w;
    float* u  = (float*)(w + B_BYTES);
    float* ps = (float*)(w + B_BYTES + U_BYTES);
    prep_u_kernel<<<dim3(4, 32), 256, 0, stream>>>(hidden, attn_w, attn_b, u);
    prep_w2_flat_kernel<<<1024, 256, 0, stream>>>(attn_w, Bt);
    gemm_fused_kernel<<<dim3(NCB, M_TOT / 128), 256, 0, stream>>>(enc, Bt, u, v, ps);
    softmax_kernel<<<B_SZ, 256, 0, stream>>>(ps, out);
  }
}